// Round 8
// baseline (273.166 us; speedup 1.0000x reference)
//
#include <hip/hip_runtime.h>

#define TOK 8192   // B*S
#define DIM 512    // D
#define NE  32     // experts
#define KTOT (NE * DIM)

#define BM 128
#define BN 64
#define BK 64

typedef float f32x4 __attribute__((ext_vector_type(4)));
typedef short s16x8 __attribute__((ext_vector_type(8)));

typedef const void __attribute__((address_space(1)))* gp1_t;
typedef void __attribute__((address_space(3)))* lp3_t;

__device__ __forceinline__ void gl_lds16(const void* g, void* l) {
    __builtin_amdgcn_global_load_lds((gp1_t)g, (lp3_t)l, 16, 0, 0);
}

__device__ __forceinline__ ushort f2bf(float f) {
    unsigned u = __builtin_bit_cast(unsigned, f);
    unsigned r = (u + 0x7fffu + ((u >> 16) & 1u)) >> 16;
    return (ushort)r;
}

// ---- fused prep: blocks [0,2048) transpose+convert W; [2048,3072) gates+cvt x
// Gates are written TRANSPOSED: G2[e][tok] (coalesced Gs staging in the GEMM).
__global__ __launch_bounds__(256) void k_prep(const float* __restrict__ w,
                                              ushort* __restrict__ wt,
                                              const float* __restrict__ x,
                                              const float* __restrict__ gw,
                                              const float* __restrict__ gb,
                                              float* __restrict__ G2,
                                              ushort* __restrict__ xb) {
    __shared__ __align__(16) char smem[64 * 65 * 4];
    const int bx = blockIdx.x;
    const int tid = threadIdx.x;
    if (bx < 2048) {
        float (*tile)[65] = (float(*)[65])smem;
        const int e = bx >> 6;
        const int f0 = ((bx >> 3) & 7) * 64;
        const int d0 = (bx & 7) * 64;
        const int tx = tid & 63, ty = tid >> 6;  // ty 0..3
        const float* we = w + (size_t)e * DIM * DIM;
#pragma unroll
        for (int i = ty; i < 64; i += 4)
            tile[i][tx] = we[(size_t)(d0 + i) * DIM + f0 + tx];
        __syncthreads();
#pragma unroll
        for (int i = ty; i < 64; i += 4)
            wt[(size_t)(f0 + i) * KTOT + e * DIM + d0 + tx] = f2bf(tile[tx][i]);
    } else {
        float* xs = (float*)smem;
        const int t0 = (bx - 2048) * 8;
        const float* xBase = x + (size_t)t0 * DIM;
#pragma unroll
        for (int k = 0; k < 4; ++k) {
            int i4 = (k * 256 + tid) * 4;
            float4 v = *(const float4*)(xBase + i4);
            xs[i4 + 0] = v.x; xs[i4 + 1] = v.y; xs[i4 + 2] = v.z; xs[i4 + 3] = v.w;
            ushort4 o;
            o.x = f2bf(v.x); o.y = f2bf(v.y); o.z = f2bf(v.z); o.w = f2bf(v.w);
            *(ushort4*)(xb + (size_t)t0 * DIM + i4) = o;
        }
        __syncthreads();
        const int tok = tid >> 5;   // 0..7
        const int e = tid & 31;
        float l = gb[e];
        const float* xr = xs + tok * DIM;
#pragma unroll 8
        for (int d = 0; d < DIM; ++d)
            l += xr[d] * gw[d * NE + e];
        float mx = l;
#pragma unroll
        for (int m = 16; m >= 1; m >>= 1) mx = fmaxf(mx, __shfl_xor(mx, m));
        float ex = expf(l - mx);
        float s = ex;
#pragma unroll
        for (int m = 16; m >= 1; m >>= 1) s += __shfl_xor(s, m);
        G2[(size_t)e * TOK + t0 + tok] = ex / s;
    }
}

// --------------- main GEMM v3: A-in-registers, B-only LDS ------------------
// Block 128x64, 4 waves of 64x32 (2m x 2n). kt-outer / e-inner: A fragments
// live in 32 VGPRs per kt, loaded straight from global (L2-hot xb) — A never
// touches LDS. B: 8 KB tiles, double-buffered global_load_lds with one-ahead
// issue (R7-proven). Gates in LDS (lgkm path; no vmcnt interaction).
// Reads/MFMA: 4 b128 per 16 MFMAs = 0.25 (was 0.75). z=2 expert split.
__global__ __launch_bounds__(256, 4) void k_moe_gemm(const ushort* __restrict__ xb,
                                                     const ushort* __restrict__ wt,
                                                     const float* __restrict__ G2,
                                                     float* __restrict__ out0,
                                                     float* __restrict__ out1) {
    __shared__ __align__(16) ushort Bs[2][BN * BK];   // 2 x 8 KB
    __shared__ float Gs[16][BM];                      // 8 KB

    const int tid = threadIdx.x;
    const int m0 = blockIdx.y * BM;
    const int n0 = blockIdx.x * BN;
    const int e0 = blockIdx.z * 16;
    float* __restrict__ dst = blockIdx.z ? out1 : out0;

    // Gs staging (coalesced: G2 is [e][tok])
    for (int i = tid; i < 16 * BM; i += 256) {
        int e = i >> 7, r = i & 127;
        Gs[e][r] = G2[(size_t)(e0 + e) * TOK + m0 + r];
    }

    const int lane = tid & 63;
    const int wave = tid >> 6;            // 0..3
    const int wm = (wave & 1) * 64;       // 2 m-positions
    const int wn = (wave >> 1) * 32;      // 2 n-positions
    const int l15 = lane & 15;
    const int q = lane >> 4;              // 0..3
    const int keyR = l15 & 7;

    // B reader byte offsets: row*128 + ((ks*4+q)^key)*16
    int rb[2][2];
#pragma unroll
    for (int j = 0; j < 2; ++j)
#pragma unroll
        for (int ks = 0; ks < 2; ++ks)
            rb[j][ks] = (wn + j * 16 + l15) * 128 + (((ks * 4 + q) ^ keyR) << 4);

    // B staging map: 256 thr x 2 chunks = 8 KB tile (rows 0..31, 32..63)
    const int srow = tid >> 3;                       // 0..31
    const int c8 = tid & 7;
    const int scol = ((c8 ^ (srow & 7)) * 8);        // swizzled global column
    const ushort* bBase = wt + (size_t)(n0 + srow) * KTOT + (size_t)e0 * DIM + scol;
    const ushort* bBase2 = bBase + (size_t)32 * KTOT;
    const int ldsOff = tid * 16;

    // A fragment pointers (per i); kt/ks become immediate offsets
    const ushort* aP[4];
#pragma unroll
    for (int i = 0; i < 4; ++i)
        aP[i] = xb + (size_t)(m0 + wm + i * 16 + l15) * DIM + q * 8;

    const f32x4 zv = {0.f, 0.f, 0.f, 0.f};
    f32x4 acc[4][2];
#pragma unroll
    for (int i = 0; i < 4; ++i)
#pragma unroll
        for (int j = 0; j < 2; ++j) acc[i][j] = zv;

    // prologue: DMA tile g=0 (kt=0, ee=0)
    gl_lds16(bBase, (char*)Bs[0] + ldsOff);
    gl_lds16(bBase2, (char*)Bs[0] + 4096 + ldsOff);
    __syncthreads();

#pragma unroll 1
    for (int kt = 0; kt < 8; ++kt) {
        // A fragments for this kt (global -> VGPR, persists across 16 experts)
        s16x8 a[4][2];
#pragma unroll
        for (int i = 0; i < 4; ++i) {
            a[i][0] = *(const s16x8*)(aP[i] + kt * 64);
            a[i][1] = *(const s16x8*)(aP[i] + kt * 64 + 32);
        }

#pragma unroll 1
        for (int ee = 0; ee < 16; ++ee) {
            const int g = kt * 16 + ee;
            // one-ahead DMA into the other buffer
            if (g + 1 < 128) {
                const int gn = g + 1;
                const ushort* bN = bBase + (size_t)(gn & 15) * DIM + (gn >> 4) * BK;
                char* bL = (char*)Bs[gn & 1] + ldsOff;
                gl_lds16(bN, bL);
                gl_lds16(bN + (size_t)32 * KTOT, bL + 4096);
            }

            const char* Bb = (const char*)Bs[g & 1];
            s16x8 b[2][2];
#pragma unroll
            for (int j = 0; j < 2; ++j) {
                b[j][0] = *(const s16x8*)(Bb + rb[j][0]);
                b[j][1] = *(const s16x8*)(Bb + rb[j][1]);
            }

#pragma unroll
            for (int i = 0; i < 4; ++i) {
                const f32x4 gt = *(const f32x4*)&Gs[ee][wm + i * 16 + q * 4];
#pragma unroll
                for (int j = 0; j < 2; ++j) {
                    f32x4 p = __builtin_amdgcn_mfma_f32_16x16x32_bf16(
                        a[i][0], b[j][0], zv, 0, 0, 0);
                    p = __builtin_amdgcn_mfma_f32_16x16x32_bf16(
                        a[i][1], b[j][1], p, 0, 0, 0);
                    acc[i][j][0] += gt[0] * p[0];
                    acc[i][j][1] += gt[1] * p[1];
                    acc[i][j][2] += gt[2] * p[2];
                    acc[i][j][3] += gt[3] * p[3];
                }
            }
            __syncthreads();   // publishes next buffer (DMA had full compute phase)
        }
    }

    // epilogue: plain stores (each element owned by exactly one lane)
#pragma unroll
    for (int i = 0; i < 4; ++i) {
        const int tl = m0 + wm + i * 16 + q * 4;
#pragma unroll
        for (int j = 0; j < 2; ++j) {
            const int f = n0 + wn + j * 16 + l15;
            float* p = dst + (size_t)tl * DIM + f;
            p[0 * DIM] = acc[i][j][0];
            p[1 * DIM] = acc[i][j][1];
            p[2 * DIM] = acc[i][j][2];
            p[3 * DIM] = acc[i][j][3];
        }
    }
}

// ---- deterministic two-phase sum: out += P (both fully written upstream) ----
__global__ __launch_bounds__(256) void k_reduce(float* __restrict__ out,
                                                const float* __restrict__ P) {
    int i = (blockIdx.x * 256 + threadIdx.x) * 4;
    float4 a = *(const float4*)(out + i);
    float4 b = *(const float4*)(P + i);
    a.x += b.x; a.y += b.y; a.z += b.z; a.w += b.w;
    *(float4*)(out + i) = a;
}

extern "C" void kernel_launch(void* const* d_in, const int* in_sizes, int n_in,
                              void* d_out, int out_size, void* d_ws, size_t ws_size,
                              hipStream_t stream) {
    const float* x  = (const float*)d_in[0];   // [8192][512]
    const float* gw = (const float*)d_in[1];   // [512][32]
    const float* gb = (const float*)d_in[2];   // [32]
    const float* w  = (const float*)d_in[3];   // [32][512][512]
    float* out = (float*)d_out;                // [8192][512] fp32

    char* ws = (char*)d_ws;
    ushort* xb = (ushort*)ws;                            //  0..8 MiB
    ushort* wt = (ushort*)(ws + (8u << 20));             //  8..24 MiB
    float*  G2 = (float*)(ws + (24u << 20));             // 24..25 MiB ([e][tok])
    float*  P  = (float*)(ws + (25u << 20));             // 25..41 MiB

    k_prep<<<dim3(2048 + TOK / 8), dim3(256), 0, stream>>>(w, wt, x, gw, gb, G2, xb);
    k_moe_gemm<<<dim3(DIM / BN, TOK / BM, 2), dim3(256), 0, stream>>>(xb, wt, G2, out, P);
    k_reduce<<<dim3(TOK * DIM / 1024), dim3(256), 0, stream>>>(out, P);
}